// Round 1
// baseline (107379.761 us; speedup 1.0000x reference)
//
#include <hip/hip_runtime.h>
#include <math.h>

#define NB  256      // batch
#define NYD 256      // y dim (D)
#define NL  1024     // latents
#define NT  512      // time steps
#define KIN (2*NYD)  // 512, gru input width

// ---------------- mask dtype probe (runtime, graph-safe) ----------------
// mode 0: int32 words {0,1}; mode 1: uint8 bytes; mode 2: float32 {0.0,1.0}
__global__ void probe_mask_kernel(const unsigned int* __restrict__ mw,
                                  int* __restrict__ flag) {
    __shared__ int not01, notf;
    if (threadIdx.x == 0) { not01 = 0; notf = 0; }
    __syncthreads();
    unsigned int v = mw[threadIdx.x];          // first 1KB of the mask buffer
    if (v > 1u) not01 = 1;
    if (v != 0u && v != 0x3f800000u) notf = 1;
    __syncthreads();
    if (threadIdx.x == 0) {
        int mode = 0;
        if (not01) mode = notf ? 1 : 2;
        *flag = mode;
    }
}

__device__ __forceinline__ int mask_at(const void* mp, int mode, int idx) {
    if (mode == 1) return ((const unsigned char*)mp)[idx] != 0;
    if (mode == 2) return ((const float*)mp)[idx] != 0.0f;
    return ((const int*)mp)[idx] != 0;
}

__device__ __forceinline__ float sigmoidf_(float x) {
    return 1.0f / (1.0f + expf(-x));
}

// ---------------- h0 = x @ W_beta.T + b_beta (one-time) ----------------
__global__ __launch_bounds__(256) void init_h_kernel(
        const float* __restrict__ x,    // [NB][1024]
        const float* __restrict__ Wb,   // [NL][1024]
        const float* __restrict__ bb,   // [NL]
        float* __restrict__ h0) {       // [NB][NL]
    int idx = blockIdx.x * 256 + threadIdx.x;   // NB*NL
    int b = idx >> 10;
    int l = idx & 1023;
    const float4* xr = (const float4*)(x + b * 1024);
    const float4* wr = (const float4*)(Wb + l * 1024);
    float acc = bb[l];
#pragma unroll 4
    for (int k = 0; k < 256; ++k) {
        float4 xv = xr[k];
        float4 wv = wr[k];
        acc += xv.x*wv.x + xv.y*wv.y + xv.z*wv.z + xv.w*wv.w;
    }
    h0[idx] = acc;
}

// ---------------- gru_in for t=0 (prev prediction = 0) ----------------
__global__ __launch_bounds__(NYD) void init_gru0_kernel(
        const float* __restrict__ y, const void* __restrict__ ymask,
        const int* __restrict__ mflag,
        float2* __restrict__ gin) {     // [NB][NYD] as (value, mask)
    int b = blockIdx.x;
    int d = threadIdx.x;
    int mode = *mflag;
    int idx = (b * NYD + d) * NT;       // t = 0
    int m = mask_at(ymask, mode, idx);
    float yv = m ? y[idx] : 0.0f;
    gin[b * NYD + d] = make_float2(yv, (float)m);
}

// ---------------- one GEMM phase of the gates kernel ----------------
// acc{r,z,n}[i] += sum_k A[b0+bg*4+i][k] * W[g*NL + l0 + lth][k], g = 0,1,2
template<int NIT>
__device__ __forceinline__ void gemm_phase(
        const float* __restrict__ A, int pitch,          // A tile base (row b0), pitch
        const float* __restrict__ W,                     // [3*NL][pitch]
        int l0, int tid, int bg, int lth,
        float (&Ash)[16][32], float (&Wsh)[3][32][32],
        float* accr, float* accz, float* accn) {
    const int arow = tid >> 3;           // 0..15
    const int akc  = (tid & 7) * 4;      // float offset in k
    float4 areg, wreg[6];
    int wrow[6], wg[6], wkc[6];
#pragma unroll
    for (int i = 0; i < 6; ++i) {
        int idx = tid + 128 * i;         // 768 float4 of W per k-step
        wkc[i]  = (idx & 7) * 4;
        wrow[i] = (idx >> 3) & 31;
        wg[i]   = idx >> 8;
    }
    // prologue: stage k0 = 0
    areg = *(const float4*)(A + arow * pitch + akc);
#pragma unroll
    for (int i = 0; i < 6; ++i)
        wreg[i] = *(const float4*)(W + (wg[i]*NL + l0 + wrow[i]) * pitch + wkc[i]);
    *(float4*)&Ash[arow][akc] = areg;
#pragma unroll
    for (int i = 0; i < 6; ++i)
        *(float4*)&Wsh[wg[i]][wrow[i]][wkc[i] ^ ((wrow[i] & 7) << 2)] = wreg[i];
    __syncthreads();

    const int wsw = (lth & 7) << 2;      // read-side XOR swizzle
    for (int it = 0; it < NIT; ++it) {
        const int k0n = (it + 1) * 32;
        if (it + 1 < NIT) {              // prefetch next tile into regs
            areg = *(const float4*)(A + arow * pitch + k0n + akc);
#pragma unroll
            for (int i = 0; i < 6; ++i)
                wreg[i] = *(const float4*)(W + (wg[i]*NL + l0 + wrow[i]) * pitch + k0n + wkc[i]);
        }
#pragma unroll
        for (int kk = 0; kk < 8; ++kk) {
            float4 wr_ = *(const float4*)&Wsh[0][lth][(kk*4) ^ wsw];
            float4 wz_ = *(const float4*)&Wsh[1][lth][(kk*4) ^ wsw];
            float4 wn_ = *(const float4*)&Wsh[2][lth][(kk*4) ^ wsw];
#pragma unroll
            for (int i = 0; i < 4; ++i) {
                float4 av = *(const float4*)&Ash[bg*4 + i][kk*4];
                accr[i] += av.x*wr_.x + av.y*wr_.y + av.z*wr_.z + av.w*wr_.w;
                accz[i] += av.x*wz_.x + av.y*wz_.y + av.z*wz_.z + av.w*wz_.w;
                accn[i] += av.x*wn_.x + av.y*wn_.y + av.z*wn_.z + av.w*wn_.w;
            }
        }
        __syncthreads();
        if (it + 1 < NIT) {
            *(float4*)&Ash[arow][akc] = areg;
#pragma unroll
            for (int i = 0; i < 6; ++i)
                *(float4*)&Wsh[wg[i]][wrow[i]][wkc[i] ^ ((wrow[i] & 7) << 2)] = wreg[i];
            __syncthreads();
        }
    }
}

// ---------------- per-step: gates + h_new ----------------
// tile: 16 b x 32 l, grid (16, 32), 128 threads (bg = tid>>5 covers 4 b each)
__global__ __launch_bounds__(128) void step_gates_kernel(
        const float* __restrict__ h_prev,  // [NB][NL]
        float* __restrict__ h_next,        // [NB][NL]
        const float* __restrict__ gin,     // [NB][KIN]
        const float* __restrict__ W_ih,    // [3NL][KIN]
        const float* __restrict__ b_ih,    // [3NL]
        const float* __restrict__ W_hh,    // [3NL][NL]
        const float* __restrict__ b_hh) {  // [3NL]
    const int b0 = blockIdx.x * 16;
    const int l0 = blockIdx.y * 32;
    const int tid = threadIdx.x;
    const int lth = tid & 31;
    const int bg  = tid >> 5;            // 0..3
    __shared__ float Ash[16][32];
    __shared__ float Wsh[3][32][32];

    float accr[4]  = {0.f, 0.f, 0.f, 0.f};
    float accz[4]  = {0.f, 0.f, 0.f, 0.f};
    float accni[4] = {0.f, 0.f, 0.f, 0.f};
    float accnh[4] = {0.f, 0.f, 0.f, 0.f};

    gemm_phase<KIN/32>(gin    + b0*KIN, KIN, W_ih, l0, tid, bg, lth, Ash, Wsh, accr, accz, accni);
    gemm_phase<NL/32 >(h_prev + b0*NL,  NL,  W_hh, l0, tid, bg, lth, Ash, Wsh, accr, accz, accnh);

    const int l = l0 + lth;
    const float br  = b_ih[l]        + b_hh[l];
    const float bz  = b_ih[NL + l]   + b_hh[NL + l];
    const float bni = b_ih[2*NL + l];
    const float bnh = b_hh[2*NL + l];
#pragma unroll
    for (int i = 0; i < 4; ++i) {
        const int b = b0 + bg*4 + i;
        float r = sigmoidf_(accr[i] + br);
        float z = sigmoidf_(accz[i] + bz);
        float n = tanhf(accni[i] + bni + r * (accnh[i] + bnh));
        float hp = h_prev[b*NL + l];
        h_next[b*NL + l] = (1.0f - z)*n + z*hp;
    }
}

// ---------------- per-step: out_t = h_new @ W_out.T + b_out, + next gru_in ----------------
// tile: 16 b x 32 d, grid (16, 8), 128 threads
__global__ __launch_bounds__(128) void step_out_kernel(
        const float* __restrict__ h,      // h_new [NB][NL]
        const float* __restrict__ W_out,  // [NYD][NL]
        const float* __restrict__ b_out,  // [NYD]
        const float* __restrict__ y,      // [NB][NYD][NT]
        const void* __restrict__ ymask,
        const int* __restrict__ mflag,
        float* __restrict__ out,          // [NB][NYD][NT]
        float2* __restrict__ gin,         // next step's gru input
        int t) {
    const int b0 = blockIdx.x * 16;
    const int d0 = blockIdx.y * 32;
    const int tid = threadIdx.x;
    const int dth = tid & 31;
    const int bg  = tid >> 5;
    __shared__ float Ash[16][32];
    __shared__ float Wsh[32][32];
    float acc[4] = {0.f, 0.f, 0.f, 0.f};

    const int arow = tid >> 3;
    const int akc  = (tid & 7) * 4;
    float4 areg, wreg[2];
    int wrow[2], wkc[2];
#pragma unroll
    for (int i = 0; i < 2; ++i) {
        int idx = tid + 128 * i;          // 256 float4 of W per k-step
        wkc[i]  = (idx & 7) * 4;
        wrow[i] = idx >> 3;               // 0..31
    }
    const float* A = h + b0 * NL;
    // prologue
    areg = *(const float4*)(A + arow * NL + akc);
#pragma unroll
    for (int i = 0; i < 2; ++i)
        wreg[i] = *(const float4*)(W_out + (d0 + wrow[i]) * NL + wkc[i]);
    *(float4*)&Ash[arow][akc] = areg;
#pragma unroll
    for (int i = 0; i < 2; ++i)
        *(float4*)&Wsh[wrow[i]][wkc[i] ^ ((wrow[i] & 7) << 2)] = wreg[i];
    __syncthreads();

    const int wsw = (dth & 7) << 2;
    for (int it = 0; it < NL/32; ++it) {
        const int k0n = (it + 1) * 32;
        if (it + 1 < NL/32) {
            areg = *(const float4*)(A + arow * NL + k0n + akc);
#pragma unroll
            for (int i = 0; i < 2; ++i)
                wreg[i] = *(const float4*)(W_out + (d0 + wrow[i]) * NL + k0n + wkc[i]);
        }
#pragma unroll
        for (int kk = 0; kk < 8; ++kk) {
            float4 wv = *(const float4*)&Wsh[dth][(kk*4) ^ wsw];
#pragma unroll
            for (int i = 0; i < 4; ++i) {
                float4 av = *(const float4*)&Ash[bg*4 + i][kk*4];
                acc[i] += av.x*wv.x + av.y*wv.y + av.z*wv.z + av.w*wv.w;
            }
        }
        __syncthreads();
        if (it + 1 < NL/32) {
            *(float4*)&Ash[arow][akc] = areg;
#pragma unroll
            for (int i = 0; i < 2; ++i)
                *(float4*)&Wsh[wrow[i]][wkc[i] ^ ((wrow[i] & 7) << 2)] = wreg[i];
            __syncthreads();
        }
    }

    const int d = d0 + dth;
    const float bo = b_out[d];
    const int mode = *mflag;
#pragma unroll
    for (int i = 0; i < 4; ++i) {
        const int b = b0 + bg*4 + i;
        float o = acc[i] + bo;
        out[(b*NYD + d)*NT + t] = o;
        if (t + 1 < NT) {
            int idx = (b*NYD + d)*NT + (t + 1);
            int m = mask_at(ymask, mode, idx);
            float yv = m ? y[idx] : o;      // teacher forcing select
            gin[b*NYD + d] = make_float2(yv, (float)m);
        }
    }
}

extern "C" void kernel_launch(void* const* d_in, const int* in_sizes, int n_in,
                              void* d_out, int out_size, void* d_ws, size_t ws_size,
                              hipStream_t stream) {
    const float* x      = (const float*)d_in[0];
    const float* y      = (const float*)d_in[1];
    const void*  ymask  = d_in[2];
    const float* W_beta = (const float*)d_in[3];
    const float* b_beta = (const float*)d_in[4];
    const float* W_ih   = (const float*)d_in[5];
    const float* b_ih   = (const float*)d_in[6];
    const float* W_hh   = (const float*)d_in[7];
    const float* b_hh   = (const float*)d_in[8];
    const float* W_out  = (const float*)d_in[9];
    const float* b_out  = (const float*)d_in[10];
    float* out = (float*)d_out;

    float*  ws    = (float*)d_ws;
    float*  hbuf0 = ws;                          // [NB*NL]
    float*  hbuf1 = ws + NB*NL;                  // [NB*NL]
    float2* gin   = (float2*)(ws + 2*NB*NL);     // [NB*NYD] (value, mask)
    int*    mflag = (int*)(ws + 2*NB*NL + 2*NB*NYD);

    probe_mask_kernel<<<1, 256, 0, stream>>>((const unsigned int*)ymask, mflag);
    init_h_kernel<<<NB*NL/256, 256, 0, stream>>>(x, W_beta, b_beta, hbuf0);
    init_gru0_kernel<<<NB, NYD, 0, stream>>>(y, ymask, mflag, gin);

    for (int t = 0; t < NT; ++t) {
        float* hp = (t & 1) ? hbuf1 : hbuf0;
        float* hn = (t & 1) ? hbuf0 : hbuf1;
        dim3 ggrid(16, 32);   // b-tiles x l-tiles
        step_gates_kernel<<<ggrid, 128, 0, stream>>>(
            hp, hn, (const float*)gin, W_ih, b_ih, W_hh, b_hh);
        dim3 ogrid(16, 8);    // b-tiles x d-tiles
        step_out_kernel<<<ogrid, 128, 0, stream>>>(
            hn, W_out, b_out, y, ymask, mflag, out, gin, t);
    }
}